// Round 3
// baseline (252.981 us; speedup 1.0000x reference)
//
#include <hip/hip_runtime.h>

// Problem constants (from reference)
constexpr int B  = 8;
constexpr int T  = 256;
constexpr int U1 = 65;
constexpr int DK = 640;   // D_ENC == D_pred
constexpr int V  = 1024;

constexpr int M_ENC  = B * T;    // 2048
constexpr int M_PRED = B * U1;   // 520

typedef float f32x4 __attribute__((ext_vector_type(4)));

__device__ __forceinline__ void fma4(float a, const float4& wv, float4& c) {
    c.x = fmaf(a, wv.x, c.x);
    c.y = fmaf(a, wv.y, c.y);
    c.z = fmaf(a, wv.z, c.z);
    c.w = fmaf(a, wv.w, c.w);
}

// ---------------------------------------------------------------------------
// pred_proj = pred @ W[640:] + bias        (520 x 1024)
// Grid: 33 row-tiles x 8 col-parts = 264 blocks, 256 threads.
// Each block: 16 rows x 128 cols. Thread: 2 rows x 1 float4 col.
// ---------------------------------------------------------------------------
constexpr int P_TM   = 16;
constexpr int P_NRB  = (M_PRED + P_TM - 1) / P_TM;   // 33
constexpr int P_CSPL = 8;                            // 128 cols per block
constexpr int P_NC4  = (V / P_CSPL) / 4;             // 32 float4

__global__ __launch_bounds__(256) void pred_proj_kernel(
    const float* __restrict__ pred, const float* __restrict__ W,
    const float* __restrict__ bias, float* __restrict__ pred_proj)
{
    __shared__ float a_s[P_TM * DK];   // 40 KB

    const int tid     = threadIdx.x;
    const int rb      = blockIdx.x / P_CSPL;
    const int colpart = blockIdx.x % P_CSPL;
    const int row0    = rb * P_TM;

    // stage 16 pred rows
    {
        const float4* Ag = reinterpret_cast<const float4*>(pred + (size_t)row0 * DK);
        float4* As = reinterpret_cast<float4*>(a_s);
        const int nf4 = P_TM * DK / 4;               // 2560
        for (int i = tid; i < nf4; i += 256) {
            int r = i / (DK / 4);
            float4 v = make_float4(0.f, 0.f, 0.f, 0.f);
            if (row0 + r < M_PRED) v = Ag[i];
            As[i] = v;
        }
    }
    __syncthreads();

    const int tx = tid & (P_NC4 - 1);   // 0..31  float4 col within part
    const int rg = tid >> 5;            // 0..7   row group (2 rows each)

    float4 acc0 = make_float4(0.f, 0.f, 0.f, 0.f);
    float4 acc1 = make_float4(0.f, 0.f, 0.f, 0.f);

    const float4* W4 = reinterpret_cast<const float4*>(W + (size_t)DK * V)
                       + (size_t)colpart * P_NC4 + tx;

    for (int d = 0; d < DK; d += 4) {
        float4 w0 = W4[(size_t)(d + 0) * (V / 4)];
        float4 w1 = W4[(size_t)(d + 1) * (V / 4)];
        float4 w2 = W4[(size_t)(d + 2) * (V / 4)];
        float4 w3 = W4[(size_t)(d + 3) * (V / 4)];
        #pragma unroll
        for (int r = 0; r < 2; ++r) {
            const float4 av = *reinterpret_cast<const float4*>(
                &a_s[(rg * 2 + r) * DK + d]);
            float4& c = r ? acc1 : acc0;
            fma4(av.x, w0, c);
            fma4(av.y, w1, c);
            fma4(av.z, w2, c);
            fma4(av.w, w3, c);
        }
    }

    const float4 bv = reinterpret_cast<const float4*>(bias)[colpart * P_NC4 + tx];
    #pragma unroll
    for (int r = 0; r < 2; ++r) {
        const int row = row0 + rg * 2 + r;
        if (row < M_PRED) {
            float4 o = r ? acc1 : acc0;
            o.x += bv.x; o.y += bv.y; o.z += bv.z; o.w += bv.w;
            reinterpret_cast<float4*>(pred_proj)[(size_t)row * (V / 4)
                + colpart * P_NC4 + tx] = o;
        }
    }
}

// ---------------------------------------------------------------------------
// Fused: enc_proj rows computed in registers, broadcast-added to pred_proj,
// streamed to out. enc_proj never hits memory.
// Grid: 2048/8 = 256 blocks, 256 threads. Block: 8 enc rows x 1024 cols.
// Thread: 8 rows x 1 float4 col (acc = 32 VGPRs).
// ---------------------------------------------------------------------------
constexpr int F_TM = 8;                 // enc rows per block

__global__ __launch_bounds__(256) void fused_enc_bcast_kernel(
    const float* __restrict__ enc, const float* __restrict__ W,
    const float* __restrict__ pred_proj, float* __restrict__ out)
{
    __shared__ float a_s[F_TM * DK];    // 20 KB

    const int tid  = threadIdx.x;
    const int row0 = blockIdx.x * F_TM; // global bt row base

    // stage 8 enc rows (contiguous 20 KB)
    {
        const float4* Ag = reinterpret_cast<const float4*>(enc + (size_t)row0 * DK);
        float4* As = reinterpret_cast<float4*>(a_s);
        const int nf4 = F_TM * DK / 4;               // 1280
        for (int i = tid; i < nf4; i += 256) As[i] = Ag[i];
    }
    __syncthreads();

    float4 acc[F_TM];
    #pragma unroll
    for (int r = 0; r < F_TM; ++r) acc[r] = make_float4(0.f, 0.f, 0.f, 0.f);

    // thread owns float4 col = tid (0..255) -> all 1024 cols covered
    const float4* W4 = reinterpret_cast<const float4*>(W) + tid;

    for (int d = 0; d < DK; d += 4) {
        float4 w0 = W4[(size_t)(d + 0) * (V / 4)];
        float4 w1 = W4[(size_t)(d + 1) * (V / 4)];
        float4 w2 = W4[(size_t)(d + 2) * (V / 4)];
        float4 w3 = W4[(size_t)(d + 3) * (V / 4)];
        #pragma unroll
        for (int r = 0; r < F_TM; ++r) {
            const float4 av = *reinterpret_cast<const float4*>(
                &a_s[r * DK + d]);                   // block-uniform -> broadcast
            fma4(av.x, w0, acc[r]);
            fma4(av.y, w1, acc[r]);
            fma4(av.z, w2, acc[r]);
            fma4(av.w, w3, acc[r]);
        }
    }

    // write phase: out[row][u][:] = acc[r] + pred_proj[b][u][:]
    const int b = row0 >> 8;                         // T = 256
    const f32x4* p4 = reinterpret_cast<const f32x4*>(pred_proj)
                      + (size_t)b * U1 * (V / 4) + tid;

    #pragma unroll
    for (int r = 0; r < F_TM; ++r) {
        const int row = row0 + r;
        f32x4* o4 = reinterpret_cast<f32x4*>(out)
                    + ((size_t)row * U1) * (V / 4) + tid;
        const f32x4 e = { acc[r].x, acc[r].y, acc[r].z, acc[r].w };
        #pragma unroll 4
        for (int u = 0; u < U1; ++u) {
            f32x4 p = p4[(size_t)u * (V / 4)];
            f32x4 o = e + p;
            __builtin_nontemporal_store(o, &o4[(size_t)u * (V / 4)]);
        }
    }
}

extern "C" void kernel_launch(void* const* d_in, const int* in_sizes, int n_in,
                              void* d_out, int out_size, void* d_ws, size_t ws_size,
                              hipStream_t stream)
{
    const float* enc  = (const float*)d_in[0];   // (8,256,640)
    const float* pred = (const float*)d_in[1];   // (8,65,640)
    const float* W    = (const float*)d_in[2];   // (1280,1024)
    const float* bias = (const float*)d_in[3];   // (1024,)
    float* out = (float*)d_out;                  // (8,256,65,1024)

    float* pred_proj = (float*)d_ws;             // 520*1024 f32 = 2.1 MiB

    pred_proj_kernel<<<P_NRB * P_CSPL, 256, 0, stream>>>(pred, W, bias, pred_proj);

    fused_enc_bcast_kernel<<<M_ENC / F_TM, 256, 0, stream>>>(enc, W, pred_proj, out);
}

// Round 4
// 207.025 us; speedup vs baseline: 1.2220x; 1.2220x over previous
//
#include <hip/hip_runtime.h>

// Problem constants (from reference)
constexpr int B  = 8;
constexpr int T  = 256;
constexpr int U1 = 65;
constexpr int DK = 640;   // D_ENC == D_pred
constexpr int V  = 1024;

constexpr int M_ENC  = B * T;    // 2048
constexpr int M_PRED = B * U1;   // 520

constexpr int TM = 16;                              // rows per block tile
constexpr int NB_ENC  = M_ENC / TM;                 // 128
constexpr int NB_PRED = (M_PRED + TM - 1) / TM;     // 33
constexpr int COLSPLIT = 2;                         // 512 cols per block
constexpr int NCOL4 = (V / COLSPLIT) / 4;           // 128 float4 per col-half

typedef float f32x4 __attribute__((ext_vector_type(4)));

__device__ __forceinline__ void fma4(float a, const float4& wv, float4& c) {
    c.x = fmaf(a, wv.x, c.x);
    c.y = fmaf(a, wv.y, c.y);
    c.z = fmaf(a, wv.z, c.z);
    c.w = fmaf(a, wv.w, c.w);
}

// ---------------------------------------------------------------------------
// enc_proj = enc @ W[:640]; pred_proj = pred @ W[640:] + bias
// Grid: (NB_ENC + NB_PRED) * COLSPLIT = 322 blocks, 512 threads (8 waves).
// Block: 16 rows x 512 cols. Thread: 4 rows x 1 float4 col.
// ---------------------------------------------------------------------------
__global__ __launch_bounds__(512) void proj_kernel(
    const float* __restrict__ enc, const float* __restrict__ pred,
    const float* __restrict__ W, const float* __restrict__ bias,
    float* __restrict__ enc_proj, float* __restrict__ pred_proj)
{
    __shared__ float a_s[TM * DK];   // 40 KB

    const int tid      = threadIdx.x;
    const int rowblock = blockIdx.x >> 1;           // which 16-row tile
    const int colhalf  = blockIdx.x & 1;            // which 512-col half

    const bool isEnc = (rowblock < NB_ENC);
    const float* A   = isEnc ? enc : pred;
    float* O         = isEnc ? enc_proj : pred_proj;
    const float* Wb  = isEnc ? W : (W + (size_t)DK * V);
    const int M      = isEnc ? M_ENC : M_PRED;
    const int row0   = (isEnc ? rowblock : (rowblock - NB_ENC)) * TM;

    // ---- stage A tile (16 rows x 640 f32) into LDS ----
    {
        const float4* Ag = reinterpret_cast<const float4*>(A + (size_t)row0 * DK);
        float4* As = reinterpret_cast<float4*>(a_s);
        const int nf4 = TM * DK / 4;                // 2560
        for (int i = tid; i < nf4; i += 512) {
            int r = i / (DK / 4);                   // row within tile
            float4 v = make_float4(0.f, 0.f, 0.f, 0.f);
            if (row0 + r < M) v = Ag[i];
            As[i] = v;
        }
    }
    __syncthreads();

    // tx = col float4 slot (0..127), rg = row group (0..3 -> 4 rows each)
    const int tx = tid & (NCOL4 - 1);
    const int rg = tid >> 7;                        // wave-uniform

    float4 acc[4];
    #pragma unroll
    for (int r = 0; r < 4; ++r) acc[r] = make_float4(0.f, 0.f, 0.f, 0.f);

    const float4* W4 = reinterpret_cast<const float4*>(Wb)
                       + (size_t)colhalf * NCOL4 + tx;   // column of W, stride V/4 per d

    for (int d = 0; d < DK; d += 4) {
        float4 w0 = W4[(size_t)(d + 0) * (V / 4)];
        float4 w1 = W4[(size_t)(d + 1) * (V / 4)];
        float4 w2 = W4[(size_t)(d + 2) * (V / 4)];
        float4 w3 = W4[(size_t)(d + 3) * (V / 4)];
        #pragma unroll
        for (int r = 0; r < 4; ++r) {
            const float4 av = *reinterpret_cast<const float4*>(
                &a_s[(rg * 4 + r) * DK + d]);       // wave-uniform -> LDS broadcast
            fma4(av.x, w0, acc[r]);
            fma4(av.y, w1, acc[r]);
            fma4(av.z, w2, acc[r]);
            fma4(av.w, w3, acc[r]);
        }
    }

    // ---- epilogue: (+bias for pred rows), float4 store ----
    float4 bv = make_float4(0.f, 0.f, 0.f, 0.f);
    if (!isEnc) bv = reinterpret_cast<const float4*>(bias)[colhalf * NCOL4 + tx];

    #pragma unroll
    for (int r = 0; r < 4; ++r) {
        const int row = row0 + rg * 4 + r;
        if (row < M) {
            float4 o = acc[r];
            o.x += bv.x; o.y += bv.y; o.z += bv.z; o.w += bv.w;
            reinterpret_cast<float4*>(O)[(size_t)row * (V / 4) + colhalf * NCOL4 + tx] = o;
        }
    }
}

// ---------------------------------------------------------------------------
// out[b,t,u,v] = enc_proj[b,t,v] + pred_proj[b,u,v]   (bias already folded in)
// Grid: B*T = 2048 blocks, 256 threads; thread owns one float4 of V.
// 8 blocks/CU -> 32 waves/CU; write stream fully TLP-covered.
// ---------------------------------------------------------------------------
__global__ __launch_bounds__(256) void bcast_kernel(
    const float* __restrict__ enc_proj, const float* __restrict__ pred_proj,
    float* __restrict__ out)
{
    const int bt  = blockIdx.x;          // 0..2047
    const int b   = bt >> 8;             // T = 256
    const int tid = threadIdx.x;

    const f32x4* e4 = reinterpret_cast<const f32x4*>(enc_proj) + (size_t)bt * (V / 4);
    const f32x4* p4 = reinterpret_cast<const f32x4*>(pred_proj) + (size_t)b * U1 * (V / 4);
    f32x4* o4       = reinterpret_cast<f32x4*>(out) + (size_t)bt * U1 * (V / 4);

    const f32x4 e = e4[tid];

    #pragma unroll 4
    for (int u = 0; u < U1; ++u) {
        f32x4 p = p4[(size_t)u * (V / 4) + tid];
        f32x4 o = e + p;
        __builtin_nontemporal_store(o, &o4[(size_t)u * (V / 4) + tid]);
    }
}

extern "C" void kernel_launch(void* const* d_in, const int* in_sizes, int n_in,
                              void* d_out, int out_size, void* d_ws, size_t ws_size,
                              hipStream_t stream)
{
    const float* enc  = (const float*)d_in[0];   // (8,256,640)
    const float* pred = (const float*)d_in[1];   // (8,65,640)
    const float* W    = (const float*)d_in[2];   // (1280,1024)
    const float* bias = (const float*)d_in[3];   // (1024,)
    float* out = (float*)d_out;                  // (8,256,65,1024)

    float* enc_proj  = (float*)d_ws;                         // 2048*1024 f32 = 8 MiB
    float* pred_proj = enc_proj + (size_t)M_ENC * V;         // 520*1024  f32 = 2 MiB

    proj_kernel<<<(NB_ENC + NB_PRED) * COLSPLIT, 512, 0, stream>>>(
        enc, pred, W, bias, enc_proj, pred_proj);

    bcast_kernel<<<M_ENC, 256, 0, stream>>>(enc_proj, pred_proj, out);
}

// Round 5
// 176.238 us; speedup vs baseline: 1.4354x; 1.1747x over previous
//
#include <hip/hip_runtime.h>

// Problem constants (from reference)
constexpr int B  = 8;
constexpr int T  = 256;
constexpr int U1 = 65;
constexpr int DK = 640;   // D_ENC == D_pred
constexpr int V  = 1024;

constexpr int M_ENC  = B * T;    // 2048
constexpr int M_PRED = B * U1;   // 520

constexpr int TM = 16;                              // rows per block tile
constexpr int NB_ENC  = M_ENC / TM;                 // 128
constexpr int NB_PRED = (M_PRED + TM - 1) / TM;     // 33
constexpr int COLSPLIT = 4;                         // 256 cols per block
constexpr int NCOL4 = (V / COLSPLIT) / 4;           // 64 float4 per col-part

typedef float f32x4 __attribute__((ext_vector_type(4)));

__device__ __forceinline__ void fma4(float a, const float4& wv, float4& c) {
    c.x = fmaf(a, wv.x, c.x);
    c.y = fmaf(a, wv.y, c.y);
    c.z = fmaf(a, wv.z, c.z);
    c.w = fmaf(a, wv.w, c.w);
}

// ---------------------------------------------------------------------------
// enc_proj = enc @ W[:640]; pred_proj = pred @ W[640:] + bias
// Grid: (NB_ENC + NB_PRED) * COLSPLIT = 644 blocks, 256 threads (4 waves).
// Block: 16 rows x 256 cols. Thread: 4 rows x 1 float4 col (acc 16 VGPR).
// 644 blocks = 2.5 blocks/CU -> ~10 waves/CU: W-load latency hidden by TLP.
// ---------------------------------------------------------------------------
__global__ __launch_bounds__(256) void proj_kernel(
    const float* __restrict__ enc, const float* __restrict__ pred,
    const float* __restrict__ W, const float* __restrict__ bias,
    float* __restrict__ enc_proj, float* __restrict__ pred_proj)
{
    __shared__ float a_s[TM * DK];   // 40 KB

    const int tid      = threadIdx.x;
    const int rowblock = blockIdx.x >> 2;           // which 16-row tile
    const int colpart  = blockIdx.x & 3;            // which 256-col part

    const bool isEnc = (rowblock < NB_ENC);
    const float* A   = isEnc ? enc : pred;
    float* O         = isEnc ? enc_proj : pred_proj;
    const float* Wb  = isEnc ? W : (W + (size_t)DK * V);
    const int M      = isEnc ? M_ENC : M_PRED;
    const int row0   = (isEnc ? rowblock : (rowblock - NB_ENC)) * TM;

    // ---- stage A tile (16 rows x 640 f32) into LDS ----
    {
        const float4* Ag = reinterpret_cast<const float4*>(A + (size_t)row0 * DK);
        float4* As = reinterpret_cast<float4*>(a_s);
        const int nf4 = TM * DK / 4;                // 2560
        for (int i = tid; i < nf4; i += 256) {
            int r = i / (DK / 4);                   // row within tile
            float4 v = make_float4(0.f, 0.f, 0.f, 0.f);
            if (row0 + r < M) v = Ag[i];
            As[i] = v;
        }
    }
    __syncthreads();

    // tx = col float4 slot (0..63), rg = row group (0..3 -> 4 rows each)
    const int tx = tid & (NCOL4 - 1);
    const int rg = tid >> 6;                        // wave-uniform

    float4 acc[4];
    #pragma unroll
    for (int r = 0; r < 4; ++r) acc[r] = make_float4(0.f, 0.f, 0.f, 0.f);

    const float4* W4 = reinterpret_cast<const float4*>(Wb)
                       + (size_t)colpart * NCOL4 + tx;   // column of W, stride V/4 per d

    #pragma unroll 2
    for (int d = 0; d < DK; d += 4) {
        float4 w0 = W4[(size_t)(d + 0) * (V / 4)];
        float4 w1 = W4[(size_t)(d + 1) * (V / 4)];
        float4 w2 = W4[(size_t)(d + 2) * (V / 4)];
        float4 w3 = W4[(size_t)(d + 3) * (V / 4)];
        #pragma unroll
        for (int r = 0; r < 4; ++r) {
            const float4 av = *reinterpret_cast<const float4*>(
                &a_s[(rg * 4 + r) * DK + d]);       // wave-uniform -> LDS broadcast
            fma4(av.x, w0, acc[r]);
            fma4(av.y, w1, acc[r]);
            fma4(av.z, w2, acc[r]);
            fma4(av.w, w3, acc[r]);
        }
    }

    // ---- epilogue: (+bias for pred rows), float4 store ----
    float4 bv = make_float4(0.f, 0.f, 0.f, 0.f);
    if (!isEnc) bv = reinterpret_cast<const float4*>(bias)[colpart * NCOL4 + tx];

    #pragma unroll
    for (int r = 0; r < 4; ++r) {
        const int row = row0 + rg * 4 + r;
        if (row < M) {
            float4 o = acc[r];
            o.x += bv.x; o.y += bv.y; o.z += bv.z; o.w += bv.w;
            reinterpret_cast<float4*>(O)[(size_t)row * (V / 4) + colpart * NCOL4 + tx] = o;
        }
    }
}

// ---------------------------------------------------------------------------
// out[b,t,u,v] = enc_proj[b,t,v] + pred_proj[b,u,v]   (bias already folded in)
// Grid: B*T = 2048 blocks, 256 threads; thread owns one float4 of V.
// 8 blocks/CU -> 32 waves/CU; write stream fully TLP-covered.
// ---------------------------------------------------------------------------
__global__ __launch_bounds__(256) void bcast_kernel(
    const float* __restrict__ enc_proj, const float* __restrict__ pred_proj,
    float* __restrict__ out)
{
    const int bt  = blockIdx.x;          // 0..2047
    const int b   = bt >> 8;             // T = 256
    const int tid = threadIdx.x;

    const f32x4* e4 = reinterpret_cast<const f32x4*>(enc_proj) + (size_t)bt * (V / 4);
    const f32x4* p4 = reinterpret_cast<const f32x4*>(pred_proj) + (size_t)b * U1 * (V / 4);
    f32x4* o4       = reinterpret_cast<f32x4*>(out) + (size_t)bt * U1 * (V / 4);

    const f32x4 e = e4[tid];

    #pragma unroll 4
    for (int u = 0; u < U1; ++u) {
        f32x4 p = p4[(size_t)u * (V / 4) + tid];
        f32x4 o = e + p;
        __builtin_nontemporal_store(o, &o4[(size_t)u * (V / 4) + tid]);
    }
}

extern "C" void kernel_launch(void* const* d_in, const int* in_sizes, int n_in,
                              void* d_out, int out_size, void* d_ws, size_t ws_size,
                              hipStream_t stream)
{
    const float* enc  = (const float*)d_in[0];   // (8,256,640)
    const float* pred = (const float*)d_in[1];   // (8,65,640)
    const float* W    = (const float*)d_in[2];   // (1280,1024)
    const float* bias = (const float*)d_in[3];   // (1024,)
    float* out = (float*)d_out;                  // (8,256,65,1024)

    float* enc_proj  = (float*)d_ws;                         // 2048*1024 f32 = 8 MiB
    float* pred_proj = enc_proj + (size_t)M_ENC * V;         // 520*1024  f32 = 2 MiB

    proj_kernel<<<(NB_ENC + NB_PRED) * COLSPLIT, 256, 0, stream>>>(
        enc, pred, W, bias, enc_proj, pred_proj);

    bcast_kernel<<<M_ENC, 256, 0, stream>>>(enc_proj, pred_proj, out);
}